// Round 3
// baseline (207.179 us; speedup 1.0000x reference)
//
#include <hip/hip_runtime.h>
#include <math.h>

// Problem constants (from setup_inputs): x is (B=32, C=3, H=512, W=512) fp32.
constexpr int B = 32;
constexpr int C = 3;
constexpr int H = 512;
constexpr int W = 512;
constexpr int HW = H * W;

// ---------------------------------------------------------------------------
// Single-kernel affine warp, bilinear, zero padding.
//
// Affine reduction: overall = fw^-1 * diag(1/l1,1/l2,1) * fw; translation
// cancels, leaving a pure 2x2 linear map (computed fp64 by thread 0,
// broadcast via LDS).
//
// R2 = R1 minus nontemporal stores (A/B isolation). [Resubmit: R2 bench was
// an infra failure — container acquisition failed; kernel never ran.]
// R1 post-mortem: XCD swizzle worked (FETCH 113->43 MB) but dur rose
// 63.6->79.3 us with Occupancy UP and VALUBusy DOWN -> store-side
// backpressure from NT stores bypassing L2 write buffering. Reverting to
// plain stores; keeping:
//  1. XCD-batch affinity swizzle (xcd = lid & 7 owns batches {x,x+8,x+16,x+24})
//     -> one 3 MiB batch lives in that XCD's 4 MiB L2; gathers are local L2 hits.
//  2. Branchless gathers: validity folded into bilinear weights, clamped
//     always-in-bounds addresses, no exec-mask toggles around the 24 loads.
// ---------------------------------------------------------------------------
__global__ __launch_bounds__(256)
void warp_kernel(const float* __restrict__ x,
                 const float* __restrict__ thetas,
                 const float* __restrict__ l1s,
                 const float* __restrict__ l2s,
                 float* __restrict__ out) {
    // --- XCD-affinity decode: lid -> (batch, row-pair) ---
    const int lid  = blockIdx.x;          // 0..8191
    const int xcd  = lid & 7;             // dispatch round-robins XCDs
    const int slot = lid >> 3;            // 0..1023 sequential per XCD
    const int b    = xcd + ((slot >> 8) << 3);  // batches {xcd,xcd+8,xcd+16,xcd+24}
    const int hb   = slot & 255;          // row-pair within batch

    __shared__ float sc[4];
    if (threadIdx.x == 0) {
        double th = -(double)thetas[b];
        double c = cos(th), s = sin(th);
        double a = 1.0 / (double)l1s[b];
        double d = 1.0 / (double)l2s[b];
        sc[0] = (float)(a * c * c + d * s * s);
        sc[1] = (float)(c * s * (d - a));
        sc[2] = sc[1];
        sc[3] = (float)(a * s * s + d * c * c);
    }
    __syncthreads();
    const float t00 = sc[0], t01 = sc[1], t10 = sc[2], t11 = sc[3];

    const int tid   = threadIdx.x;
    const int lane  = tid & 63;
    const int wv    = tid >> 6;                 // wave id 0..3
    const int h     = (hb << 1) | (wv >> 1);
    const int wbase = (wv & 1) << 8;            // 0 or 256

    const float Y = ((float)h + 0.5f) * (2.0f / (float)H) - 1.0f;

    // ---- geometry for the 4 pixels: addresses + masked weights ----
    int   row0[4], row1[4];
    bool  xeq[4];
    float w00[4], w01[4], w10[4], w11[4];
    bool any_valid = false;

    #pragma unroll
    for (int j = 0; j < 4; ++j) {
        const int w = wbase + (j << 6) + lane;
        const float X = ((float)w + 0.5f) * (2.0f / (float)W) - 1.0f;
        const float gx = (t00 * X + t01 * Y + 1.0f) * ((float)W * 0.5f) - 0.5f;
        const float gy = (t10 * X + t11 * Y + 1.0f) * ((float)H * 0.5f) - 0.5f;

        const float x0f = floorf(gx), y0f = floorf(gy);
        const float wx1 = gx - x0f, wx0 = 1.0f - wx1;
        const float wy1 = gy - y0f, wy0 = 1.0f - wy1;

        const int x0 = (int)x0f, y0 = (int)y0f;
        const int x1 = x0 + 1,  y1 = y0 + 1;

        const bool vx0 = ((unsigned)x0 < (unsigned)W);
        const bool vx1 = ((unsigned)x1 < (unsigned)W);
        const bool vy0 = ((unsigned)y0 < (unsigned)H);
        const bool vy1 = ((unsigned)y1 < (unsigned)H);

        const int xbj = min(max(x0, 0), W - 2);   // float2 base, always in-bounds
        xeq[j] = (x0 == xbj);

        row0[j] = min(max(y0, 0), H - 1) * W + xbj;
        row1[j] = min(max(y1, 0), H - 1) * W + xbj;

        // Fold validity into weights: invalid tap => weight 0; the loaded
        // (clamped) value is a finite float, so v * 0 == 0 exactly.
        w00[j] = (vy0 && vx0) ? wy0 * wx0 : 0.0f;
        w01[j] = (vy0 && vx1) ? wy0 * wx1 : 0.0f;
        w10[j] = (vy1 && vx0) ? wy1 * wx0 : 0.0f;
        w11[j] = (vy1 && vx1) ? wy1 * wx1 : 0.0f;

        any_valid = any_valid || ((vy0 || vy1) && (vx0 || vx1));
    }

    float r[C][4];
    #pragma unroll
    for (int ch = 0; ch < C; ++ch)
        #pragma unroll
        for (int j = 0; j < 4; ++j) r[ch][j] = 0.0f;

    if (any_valid) {
        const float* __restrict__ base = x + (size_t)b * C * HW;
        #pragma unroll
        for (int j = 0; j < 4; ++j) {
            float2 a0[C], a1[C];
            #pragma unroll
            for (int ch = 0; ch < C; ++ch) {
                a0[ch] = *reinterpret_cast<const float2*>(base + ch * HW + row0[j]);
                a1[ch] = *reinterpret_cast<const float2*>(base + ch * HW + row1[j]);
            }
            #pragma unroll
            for (int ch = 0; ch < C; ++ch) {
                const float v00 = xeq[j] ? a0[ch].x : a0[ch].y;
                const float v01 = xeq[j] ? a0[ch].y : a0[ch].x;
                const float v10 = xeq[j] ? a1[ch].x : a1[ch].y;
                const float v11 = xeq[j] ? a1[ch].y : a1[ch].x;
                r[ch][j] = v00 * w00[j] + v01 * w01[j] + v10 * w10[j] + v11 * w11[j];
            }
        }
    }

    const size_t obase = (size_t)b * C * HW + (size_t)h * W + (size_t)wbase + lane;
    #pragma unroll
    for (int ch = 0; ch < C; ++ch) {
        #pragma unroll
        for (int j = 0; j < 4; ++j) {
            out[obase + (size_t)ch * HW + (j << 6)] = r[ch][j];
        }
    }
}

extern "C" void kernel_launch(void* const* d_in, const int* in_sizes, int n_in,
                              void* d_out, int out_size, void* d_ws, size_t ws_size,
                              hipStream_t stream) {
    const float* x      = (const float*)d_in[0];
    const float* thetas = (const float*)d_in[1];
    const float* l1s    = (const float*)d_in[2];
    const float* l2s    = (const float*)d_in[3];
    float* out          = (float*)d_out;

    warp_kernel<<<dim3((H / 2) * B), 256, 0, stream>>>(x, thetas, l1s, l2s, out);
}

// Round 4
// 193.584 us; speedup vs baseline: 1.0702x; 1.0702x over previous
//
#include <hip/hip_runtime.h>
#include <math.h>

// Problem constants (from setup_inputs): x is (B=32, C=3, H=512, W=512) fp32.
constexpr int B = 32;
constexpr int C = 3;
constexpr int H = 512;
constexpr int W = 512;
constexpr int HW = H * W;

// ---------------------------------------------------------------------------
// Single-kernel affine warp, bilinear, zero padding.
//
// R3 = ORIGINAL baseline kernel (63.6 us/dispatch: per-tap predicated
// float2 gathers, plain stores) + ONE change: XCD-batch-affinity block
// swizzle. Clean isolation:
//   R3 vs baseline  -> effect of swizzle alone
//   R3 vs R2 (82us) -> effect of predicated vs branchless gathers
// R1/R2 post-mortem: branchless gathers (loads issued for invalid taps,
// clamped scattered addresses) were the regression — this kernel is
// gather-issue/latency bound, so extra lane requests cost time directly.
// NT stores were neutral. Swizzle keeps FETCH at 45 MB (vs 113).
//
// Affine reduction: overall = fw^-1 * diag(1/l1,1/l2,1) * fw; translation
// cancels, leaving a pure 2x2 linear map (fp64 by thread 0, LDS broadcast).
// ---------------------------------------------------------------------------
__global__ __launch_bounds__(256)
void warp_kernel(const float* __restrict__ x,
                 const float* __restrict__ thetas,
                 const float* __restrict__ l1s,
                 const float* __restrict__ l2s,
                 float* __restrict__ out) {
    // --- XCD-affinity decode: lid -> (batch, row-pair) ---
    const int lid  = blockIdx.x;          // 0..8191
    const int xcd  = lid & 7;             // dispatch round-robins XCDs
    const int slot = lid >> 3;            // 0..1023 sequential per XCD
    const int b    = xcd + ((slot >> 8) << 3);  // batches {xcd,xcd+8,xcd+16,xcd+24}
    const int hb   = slot & 255;          // row-pair within batch

    __shared__ float sc[4];
    if (threadIdx.x == 0) {
        double th = -(double)thetas[b];
        double c = cos(th), s = sin(th);
        double a = 1.0 / (double)l1s[b];
        double d = 1.0 / (double)l2s[b];
        sc[0] = (float)(a * c * c + d * s * s);
        sc[1] = (float)(c * s * (d - a));
        sc[2] = sc[1];
        sc[3] = (float)(a * s * s + d * c * c);
    }
    __syncthreads();
    const float t00 = sc[0], t01 = sc[1], t10 = sc[2], t11 = sc[3];

    const int tid   = threadIdx.x;
    const int lane  = tid & 63;
    const int wv    = tid >> 6;                 // wave id 0..3
    const int h     = (hb << 1) | (wv >> 1);
    const int wbase = (wv & 1) << 8;            // 0 or 256

    const float Y = ((float)h + 0.5f) * (2.0f / (float)H) - 1.0f;

    // ---- geometry for the 4 pixels ----
    int   xb[4], row0[4], row1[4];
    bool  xeq[4], vx0[4], vx1[4], pr0[4], pr1[4];
    float w00[4], w01[4], w10[4], w11[4];
    bool any_valid = false;

    #pragma unroll
    for (int j = 0; j < 4; ++j) {
        const int w = wbase + (j << 6) + lane;
        const float X = ((float)w + 0.5f) * (2.0f / (float)W) - 1.0f;
        const float gx = (t00 * X + t01 * Y + 1.0f) * ((float)W * 0.5f) - 0.5f;
        const float gy = (t10 * X + t11 * Y + 1.0f) * ((float)H * 0.5f) - 0.5f;

        const float x0f = floorf(gx), y0f = floorf(gy);
        const float wx1 = gx - x0f, wx0 = 1.0f - wx1;
        const float wy1 = gy - y0f, wy0 = 1.0f - wy1;

        const int x0 = (int)x0f, y0 = (int)y0f;
        const int x1 = x0 + 1,  y1 = y0 + 1;

        vx0[j] = ((unsigned)x0 < (unsigned)W);
        vx1[j] = ((unsigned)x1 < (unsigned)W);
        const bool vy0 = ((unsigned)y0 < (unsigned)H);
        const bool vy1 = ((unsigned)y1 < (unsigned)H);

        const int xbj = min(max(x0, 0), W - 2);
        xb[j]  = xbj;
        xeq[j] = (x0 == xbj);
        const bool anyx = vx0[j] || vx1[j];
        pr0[j] = vy0 && anyx;
        pr1[j] = vy1 && anyx;
        any_valid = any_valid || pr0[j] || pr1[j];

        row0[j] = min(max(y0, 0), H - 1) * W + xbj;
        row1[j] = min(max(y1, 0), H - 1) * W + xbj;

        w00[j] = wy0 * wx0; w01[j] = wy0 * wx1;
        w10[j] = wy1 * wx0; w11[j] = wy1 * wx1;
    }

    float r[C][4];
    #pragma unroll
    for (int ch = 0; ch < C; ++ch)
        #pragma unroll
        for (int j = 0; j < 4; ++j) r[ch][j] = 0.0f;

    if (any_valid) {
        const float* __restrict__ base = x + (size_t)b * C * HW;
        #pragma unroll
        for (int j = 0; j < 4; ++j) {
            #pragma unroll
            for (int ch = 0; ch < C; ++ch) {
                const float* __restrict__ p = base + ch * HW;
                float2 a0 = make_float2(0.0f, 0.0f);
                float2 a1 = make_float2(0.0f, 0.0f);
                if (pr0[j]) a0 = *reinterpret_cast<const float2*>(p + row0[j]);
                if (pr1[j]) a1 = *reinterpret_cast<const float2*>(p + row1[j]);
                const float v00 = vx0[j] ? (xeq[j] ? a0.x : a0.y) : 0.0f;
                const float v01 = vx1[j] ? (xeq[j] ? a0.y : a0.x) : 0.0f;
                const float v10 = vx0[j] ? (xeq[j] ? a1.x : a1.y) : 0.0f;
                const float v11 = vx1[j] ? (xeq[j] ? a1.y : a1.x) : 0.0f;
                r[ch][j] = v00 * w00[j] + v01 * w01[j] + v10 * w10[j] + v11 * w11[j];
            }
        }
    }

    const size_t obase = (size_t)b * C * HW + (size_t)h * W + (size_t)wbase + lane;
    #pragma unroll
    for (int ch = 0; ch < C; ++ch) {
        #pragma unroll
        for (int j = 0; j < 4; ++j) {
            out[obase + (size_t)ch * HW + (j << 6)] = r[ch][j];
        }
    }
}

extern "C" void kernel_launch(void* const* d_in, const int* in_sizes, int n_in,
                              void* d_out, int out_size, void* d_ws, size_t ws_size,
                              hipStream_t stream) {
    const float* x      = (const float*)d_in[0];
    const float* thetas = (const float*)d_in[1];
    const float* l1s    = (const float*)d_in[2];
    const float* l2s    = (const float*)d_in[3];
    float* out          = (float*)d_out;

    warp_kernel<<<dim3((H / 2) * B), 256, 0, stream>>>(x, thetas, l1s, l2s, out);
}

// Round 5
// 189.846 us; speedup vs baseline: 1.0913x; 1.0197x over previous
//
#include <hip/hip_runtime.h>
#include <math.h>

// Problem constants (from setup_inputs): x is (B=32, C=3, H=512, W=512) fp32.
constexpr int B = 32;
constexpr int C = 3;
constexpr int H = 512;
constexpr int W = 512;
constexpr int HW = H * W;

// ---------------------------------------------------------------------------
// Single-kernel affine warp, bilinear, zero padding.
//
// R4 = baseline (63.6 us: per-tap predicated float2 gathers, 2D grid, plain
// stores) + ONE change: all 24 gathers hoisted into registers BEFORE any
// use, with __launch_bounds__(256,4) so the register allocator may keep
// them all in flight (one vmcnt drain per thread instead of 4-6).
//
// Evidence trail:
//  - R1/R2: branchless gathers (+15 us) -> predication is right; kernel is
//    gather-bound, extra lane requests cost time directly.
//  - R3: XCD-batch swizzle halves FETCH (113->43 MB) but costs +3.4 us
//    (per-XCD batch imbalance; we are NOT HBM-BW-bound) -> reverted.
//  - Baseline VGPR=44 < 48 needed just to hold 24 float2 results ->
//    compiler provably serialized the gathers into small batches; this
//    round removes that serialization (latency-hiding via MLP).
//
// Affine reduction: overall = fw^-1 * diag(1/l1,1/l2,1) * fw; translation
// cancels, leaving a pure 2x2 linear map (fp64 by thread 0, LDS broadcast).
// ---------------------------------------------------------------------------
__global__ __launch_bounds__(256, 4)
void warp_kernel(const float* __restrict__ x,
                 const float* __restrict__ thetas,
                 const float* __restrict__ l1s,
                 const float* __restrict__ l2s,
                 float* __restrict__ out) {
    const int b = blockIdx.y;

    __shared__ float sc[4];
    if (threadIdx.x == 0) {
        double th = -(double)thetas[b];
        double c = cos(th), s = sin(th);
        double a = 1.0 / (double)l1s[b];
        double d = 1.0 / (double)l2s[b];
        sc[0] = (float)(a * c * c + d * s * s);
        sc[1] = (float)(c * s * (d - a));
        sc[2] = sc[1];
        sc[3] = (float)(a * s * s + d * c * c);
    }
    __syncthreads();
    const float t00 = sc[0], t01 = sc[1], t10 = sc[2], t11 = sc[3];

    const int tid   = threadIdx.x;
    const int lane  = tid & 63;
    const int wv    = tid >> 6;                 // wave id 0..3
    const int h     = (blockIdx.x << 1) | (wv >> 1);
    const int wbase = (wv & 1) << 8;            // 0 or 256

    const float Y = ((float)h + 0.5f) * (2.0f / (float)H) - 1.0f;

    // ---- geometry for the 4 pixels ----
    int   row0[4], row1[4];
    bool  xeq[4], vx0[4], vx1[4], pr0[4], pr1[4];
    float w00[4], w01[4], w10[4], w11[4];
    bool any_valid = false;

    #pragma unroll
    for (int j = 0; j < 4; ++j) {
        const int w = wbase + (j << 6) + lane;
        const float X = ((float)w + 0.5f) * (2.0f / (float)W) - 1.0f;
        const float gx = (t00 * X + t01 * Y + 1.0f) * ((float)W * 0.5f) - 0.5f;
        const float gy = (t10 * X + t11 * Y + 1.0f) * ((float)H * 0.5f) - 0.5f;

        const float x0f = floorf(gx), y0f = floorf(gy);
        const float wx1 = gx - x0f, wx0 = 1.0f - wx1;
        const float wy1 = gy - y0f, wy0 = 1.0f - wy1;

        const int x0 = (int)x0f, y0 = (int)y0f;
        const int x1 = x0 + 1,  y1 = y0 + 1;

        vx0[j] = ((unsigned)x0 < (unsigned)W);
        vx1[j] = ((unsigned)x1 < (unsigned)W);
        const bool vy0 = ((unsigned)y0 < (unsigned)H);
        const bool vy1 = ((unsigned)y1 < (unsigned)H);

        const int xbj = min(max(x0, 0), W - 2);   // float2 base, in-bounds
        xeq[j] = (x0 == xbj);
        const bool anyx = vx0[j] || vx1[j];
        pr0[j] = vy0 && anyx;
        pr1[j] = vy1 && anyx;
        any_valid = any_valid || pr0[j] || pr1[j];

        row0[j] = min(max(y0, 0), H - 1) * W + xbj;
        row1[j] = min(max(y1, 0), H - 1) * W + xbj;

        w00[j] = wy0 * wx0; w01[j] = wy0 * wx1;
        w10[j] = wy1 * wx0; w11[j] = wy1 * wx1;
    }

    float r[C][4];
    #pragma unroll
    for (int ch = 0; ch < C; ++ch)
        #pragma unroll
        for (int j = 0; j < 4; ++j) r[ch][j] = 0.0f;

    if (any_valid) {
        const float* __restrict__ base = x + (size_t)b * C * HW;

        // Phase 1: issue ALL 24 predicated gathers into registers.
        float2 a0[4][C], a1[4][C];
        #pragma unroll
        for (int j = 0; j < 4; ++j) {
            #pragma unroll
            for (int ch = 0; ch < C; ++ch) {
                a0[j][ch] = make_float2(0.0f, 0.0f);
                a1[j][ch] = make_float2(0.0f, 0.0f);
                if (pr0[j])
                    a0[j][ch] = *reinterpret_cast<const float2*>(base + ch * HW + row0[j]);
                if (pr1[j])
                    a1[j][ch] = *reinterpret_cast<const float2*>(base + ch * HW + row1[j]);
            }
        }

        // Phase 2: selects + weighted accumulation (no memory ops).
        #pragma unroll
        for (int j = 0; j < 4; ++j) {
            #pragma unroll
            for (int ch = 0; ch < C; ++ch) {
                const float v00 = vx0[j] ? (xeq[j] ? a0[j][ch].x : a0[j][ch].y) : 0.0f;
                const float v01 = vx1[j] ? (xeq[j] ? a0[j][ch].y : a0[j][ch].x) : 0.0f;
                const float v10 = vx0[j] ? (xeq[j] ? a1[j][ch].x : a1[j][ch].y) : 0.0f;
                const float v11 = vx1[j] ? (xeq[j] ? a1[j][ch].y : a1[j][ch].x) : 0.0f;
                r[ch][j] = v00 * w00[j] + v01 * w01[j] + v10 * w10[j] + v11 * w11[j];
            }
        }
    }

    const size_t obase = (size_t)b * C * HW + (size_t)h * W + (size_t)wbase + lane;
    #pragma unroll
    for (int ch = 0; ch < C; ++ch) {
        #pragma unroll
        for (int j = 0; j < 4; ++j) {
            out[obase + (size_t)ch * HW + (j << 6)] = r[ch][j];
        }
    }
}

extern "C" void kernel_launch(void* const* d_in, const int* in_sizes, int n_in,
                              void* d_out, int out_size, void* d_ws, size_t ws_size,
                              hipStream_t stream) {
    const float* x      = (const float*)d_in[0];
    const float* thetas = (const float*)d_in[1];
    const float* l1s    = (const float*)d_in[2];
    const float* l2s    = (const float*)d_in[3];
    float* out          = (float*)d_out;

    warp_kernel<<<dim3(H / 2, B), 256, 0, stream>>>(x, thetas, l1s, l2s, out);
}